// Round 1
// 213.214 us; speedup vs baseline: 1.3584x; 1.3584x over previous
//
#include <hip/hip_runtime.h>
#include <math.h>

// Problem constants
#define N_ROWS 8192
#define M_COLS 2048
#define K_DIM  1024
#define NM     ((size_t)N_ROWS * M_COLS)

#define LAM       0.9090909090909091f         // GAMMA/(GAMMA+EPS)
#define LOG_M     7.624618986159398f          // log(2048)

#define SKB 512                                // sinkhorn blocks
#define RPB (N_ROWS / SKB)                     // 16 rows per block

typedef __bf16 bf16x8 __attribute__((ext_vector_type(8)));
typedef float  f32x4  __attribute__((ext_vector_type(4)));
typedef unsigned short u16x8 __attribute__((ext_vector_type(8)));
typedef _Float16 h8 __attribute__((ext_vector_type(8)));

// d_out memory map (64 MB):
//   row r (r<8192): bytes [r*8192, r*8192+4096)  = cost/E fp16 row r (2048 halves)
//                   bytes [r*8192+4096, r*8192+8192) = "hole"
//   Xb bf16 row i (16 MB): hole i>>1, slot i&1  -> byte (i>>1)*8192 + 4096 + (i&1)*2048
//   Yb bf16 row j ( 4 MB): hole 4096+(j>>1)     -> byte 32MB + (j>>1)*8192 + 4096 + (j&1)*2048
// GEMM writes cost into even chunks while reading Xb/Yb from odd chunks (disjoint).

static __device__ __forceinline__ size_t xb_off(int i) {
    return ((size_t)(i >> 1) << 13) + 4096 + ((size_t)(i & 1) << 11);
}
static __device__ __forceinline__ size_t yb_off(int j) {
    return ((size_t)1 << 25) + ((size_t)(j >> 1) << 13) + 4096 + ((size_t)(j & 1) << 11);
}

// ---------------------------------------------------------------------------
// init: params, sigma=0, d2max=0, dist=0
// ---------------------------------------------------------------------------
__global__ void k_init(const int* __restrict__ iters, const int* __restrict__ ipe,
                       float* __restrict__ params, float* __restrict__ sigma,
                       unsigned int* __restrict__ d2max, float* __restrict__ dist)
{
    const int t = blockIdx.x * 256 + threadIdx.x;
    if (t < M_COLS) {
        sigma[t] = 0.0f;
        sigma[M_COLS + t] = 0.0f;
        sigma[2 * M_COLS + t] = 0.0f;
    }
    if (t == 0) {
        float ramp = 10.0f * (float)ipe[0];
        float rho;
        if (ramp == 0.0f) {
            rho = 1.1f;
        } else {
            float cur = fminf(fmaxf((float)iters[0], 0.0f), ramp);
            float phase = 1.0f - cur / ramp;
            rho = expf(-5.0f * phase * phase) + 0.1f;
        }
        rho = fminf(rho, 1.0f);
        params[0] = rho;
        params[1] = logf(rho) - LOG_M;   // logb = log(rho/M)
        *d2max = 0u;
        *dist = 0.0f;
    }
}

// ---------------------------------------------------------------------------
// fp32 pair -> packed bf16 (RNE)
// ---------------------------------------------------------------------------
static __device__ __forceinline__ unsigned pk_bf16(float a, float b) {
#if __has_builtin(__builtin_amdgcn_cvt_pk_bf16_f32)
    typedef __bf16 bf16x2 __attribute__((ext_vector_type(2)));
    bf16x2 r = __builtin_amdgcn_cvt_pk_bf16_f32(a, b);
    return __builtin_bit_cast(unsigned, r);
#else
    unsigned ua = __float_as_uint(a), ub = __float_as_uint(b);
    ua += 0x7FFFu + ((ua >> 16) & 1u);
    ub += 0x7FFFu + ((ub >> 16) & 1u);
    return (ua >> 16) | (ub & 0xFFFF0000u);
#endif
}

static __device__ __forceinline__ bf16x8 lds_frag(const unsigned short* p) {
    return __builtin_bit_cast(bf16x8, *(const u16x8*)p);
}

static __device__ __forceinline__ void gload16(const void* g, void* l) {
    __builtin_amdgcn_global_load_lds(
        (const __attribute__((address_space(1))) unsigned int*)g,
        (__attribute__((address_space(3))) unsigned int*)l, 16, 0, 0);
}

// ---------------------------------------------------------------------------
// per-row stats (min, sum, ||a-min||^2) + bf16 conversion into d_out holes.
// blocks 0..8191 = X rows; 8192..10239 = Y rows. 256 thr, 4 cols each.
// ---------------------------------------------------------------------------
__global__ __launch_bounds__(256) void rowstats_cvt(
    const float* __restrict__ X, const float* __restrict__ Y,
    unsigned char* __restrict__ outb,
    float* __restrict__ mx, float* __restrict__ sx, float* __restrict__ x2,
    float* __restrict__ my, float* __restrict__ sy, float* __restrict__ y2)
{
    const int b = blockIdx.x, tid = threadIdx.x;
    const bool isX = b < N_ROWS;
    const int row = isX ? b : b - N_ROWS;
    const float* src = isX ? (X + (size_t)row * K_DIM) : (Y + (size_t)row * K_DIM);
    const float4 v = ((const float4*)src)[tid];

    // bf16 convert into hole
    uint2 p; p.x = pk_bf16(v.x, v.y); p.y = pk_bf16(v.z, v.w);
    size_t off = isX ? xb_off(row) : yb_off(row);
    *(uint2*)(outb + off + (size_t)tid * 8) = p;

    float lmin = fminf(fminf(v.x, v.y), fminf(v.z, v.w));
    float lsum = v.x + v.y + v.z + v.w;
    float lsq  = v.x*v.x + v.y*v.y + v.z*v.z + v.w*v.w;

    __shared__ float rmin[256], rsum[256], rsq[256];
    rmin[tid] = lmin; rsum[tid] = lsum; rsq[tid] = lsq;
    __syncthreads();
    for (int s = 128; s > 0; s >>= 1) {
        if (tid < s) {
            rmin[tid] = fminf(rmin[tid], rmin[tid + s]);
            rsum[tid] += rsum[tid + s];
            rsq[tid]  += rsq[tid + s];
        }
        __syncthreads();
    }
    if (tid == 0) {
        float m = rmin[0], s = rsum[0], q = rsq[0];
        if (isX) { mx[row] = m; sx[row] = s; x2[row] = q - 2.f*m*s + (float)K_DIM*m*m; }
        else     { my[row] = m; sy[row] = s; y2[row] = q - 2.f*m*s + (float)K_DIM*m*m; }
    }
}

// ---------------------------------------------------------------------------
// MFMA GEMM on pre-converted bf16 + cost epilogue (fp16 store).
// 128x128 tile, 4 waves (2x2 of 64x64), BK=32, global_load_lds width 16.
// 2-phase double-buffered K-loop (T3 minimum recipe): stage next tile BEFORE
// compute of current; one vmcnt(0)+barrier per tile. XCD-swizzled block id.
// ---------------------------------------------------------------------------
__global__ __launch_bounds__(256, 4) void gemm_cost_mfma(
    float* __restrict__ gbuf,
    const float* __restrict__ mx, const float* __restrict__ sx, const float* __restrict__ x2,
    const float* __restrict__ my, const float* __restrict__ sy, const float* __restrict__ y2,
    unsigned int* __restrict__ d2max)
{
    __shared__ unsigned short Ash[2][128 * 32];   // 2 x 8 KB
    __shared__ unsigned short Bsh[2][128 * 32];   // 2 x 8 KB
    __shared__ float rmax[256];

    const unsigned char* outb = (const unsigned char*)gbuf;
    const int tid   = threadIdx.x;
    const int lane  = tid & 63;
    const int wave  = tid >> 6;
    const int wi    = wave >> 1;          // 0..1
    const int wj    = wave & 1;           // 0..1
    const int row16 = lane & 15;
    const int quad  = lane >> 4;          // 0..3

    // XCD-aware swizzle (bijective: 1024 blocks, 1024%8==0). Each XCD gets a
    // contiguous chunk of 128 blocks = 8 A-panels x all 16 B-panels ->
    // B (4 MB bf16) + 8x256KB A fit mostly in that XCD's L2.
    const int bid0 = blockIdx.y * 16 + blockIdx.x;
    const int bid  = (bid0 & 7) * 128 + (bid0 >> 3);
    const int i0 = (bid >> 4) * 128, j0 = (bid & 15) * 128;

    // staging addresses: phase p (0..1), wave w covers LDS rows (p*4+w)*16..+15
    const int chA = (lane & 3) * 16;       // byte chunk within 64 B row
    const unsigned char* pa[2];
    const unsigned char* pb[2];
    unsigned short* laA[2];                // LDS dest bases, buffer 0
    unsigned short* lbB[2];
    #pragma unroll
    for (int p = 0; p < 2; ++p) {
        const int rt = (p * 4 + wave) * 16 + (lane >> 2);   // row in tile
        pa[p] = outb + xb_off(i0 + rt) + chA;
        pb[p] = outb + yb_off(j0 + rt) + chA;
        laA[p] = &Ash[0][(p * 4 + wave) * 512];
        lbB[p] = &Bsh[0][(p * 4 + wave) * 512];
    }

    f32x4 acc[4][4];
    #pragma unroll
    for (int u = 0; u < 4; ++u)
        #pragma unroll
        for (int v = 0; v < 4; ++v) acc[u][v] = (f32x4){0.f, 0.f, 0.f, 0.f};

    // stage one BK=32 k-tile into buffer nb (0/1); advances global pointers
#define STAGE(nb) do {                                        \
        gload16(pa[0], laA[0] + (nb) * 4096);                 \
        gload16(pa[1], laA[1] + (nb) * 4096);                 \
        gload16(pb[0], lbB[0] + (nb) * 4096);                 \
        gload16(pb[1], lbB[1] + (nb) * 4096);                 \
        pa[0] += 64; pa[1] += 64; pb[0] += 64; pb[1] += 64;   \
    } while (0)

    // ds_read fragments from buffer cb and run the 4x4 MFMA cluster
#define COMPUTE(cb) do {                                                         \
        bf16x8 af[4], bfr[4];                                                    \
        _Pragma("unroll")                                                        \
        for (int t = 0; t < 4; ++t) {                                            \
            af[t]  = lds_frag(&Ash[cb][(wi * 64 + t * 16 + row16) * 32 + quad * 8]); \
            bfr[t] = lds_frag(&Bsh[cb][(wj * 64 + t * 16 + row16) * 32 + quad * 8]); \
        }                                                                        \
        _Pragma("unroll")                                                        \
        for (int ti = 0; ti < 4; ++ti)                                           \
            _Pragma("unroll")                                                    \
            for (int tj = 0; tj < 4; ++tj)                                       \
                acc[ti][tj] = __builtin_amdgcn_mfma_f32_16x16x32_bf16(           \
                    af[ti], bfr[tj], acc[ti][tj], 0, 0, 0);                      \
    } while (0)

    // prologue: tile 0 -> buf 0
    STAGE(0);
    __syncthreads();                      // drains vmcnt(0)

    // K_DIM/32 = 32 tiles total. 15 double-iterations cover t1..t30 staged,
    // t0..t29 computed; then stage t31 / compute t30; then compute t31.
#pragma unroll 1
    for (int it = 0; it < 15; ++it) {
        STAGE(1); COMPUTE(0); __syncthreads();
        STAGE(0); COMPUTE(1); __syncthreads();
    }
    STAGE(1); COMPUTE(0); __syncthreads();
    COMPUTE(1);

#undef STAGE
#undef COMPUTE

    // epilogue: C/D layout col=lane&15 (j), row=quad*4+reg (i); store fp16 cost
    _Float16* costh = (_Float16*)gbuf;
    float lmax = 0.0f;
    float myj[4], syj[4], yy[4];
    #pragma unroll
    for (int tj = 0; tj < 4; ++tj) {
        const int j = j0 + wj * 64 + tj * 16 + row16;
        myj[tj] = my[j]; syj[tj] = sy[j]; yy[tj] = y2[j];
    }
    #pragma unroll
    for (int ti = 0; ti < 4; ++ti) {
        #pragma unroll
        for (int reg = 0; reg < 4; ++reg) {
            const int i = i0 + wi * 64 + ti * 16 + quad * 4 + reg;
            const float mxi = mx[i], sxi = sx[i], xxi = x2[i];
            #pragma unroll
            for (int tj = 0; tj < 4; ++tj) {
                const int j = j0 + wj * 64 + tj * 16 + row16;
                float corr = mxi * syj[tj] + myj[tj] * sxi - (float)K_DIM * mxi * myj[tj];
                float d2 = xxi + yy[tj] - 2.0f * acc[ti][tj][reg] + 2.0f * corr;
                d2 = fmaxf(d2, 0.0f);
                lmax = fmaxf(lmax, d2);
                costh[(size_t)i * 4096 + j] = (_Float16)sqrtf(d2);
            }
        }
    }
    rmax[tid] = lmax;
    __syncthreads();
    for (int s = 128; s > 0; s >>= 1) {
        if (tid < s) rmax[tid] = fmaxf(rmax[tid], rmax[tid + s]);
        __syncthreads();
    }
    if (tid == 0) atomicMax(d2max, __float_as_uint(rmax[0]));
}

// ---------------------------------------------------------------------------
// Sinkhorn iteration on E = exp(-10*cn), matvec form.
//   t_r = sum_j E_rj u_j ; w_r = exp(-LAM*(logb + ln t_r))
//   gpart[b][j] = sum_{r in block} E_rj w_r     (fp16 partials)
// u_j is computed inline from the previous iteration's column sums:
//   u_j = N / sigma_j  (FIRST iteration: u = 1).
// FIRST: converts fp16 cost -> fp16 E in place (elementwise, race-free).
// 512 blocks x 256 threads; block = 16 rows; thread = 8 contiguous cols.
// ---------------------------------------------------------------------------
template<bool FIRST>
__global__ __launch_bounds__(256) void sk_iter(
    float* __restrict__ outbuf, const float* __restrict__ sigma,
    float* __restrict__ w, _Float16* __restrict__ gpart,
    const float* __restrict__ params, const unsigned int* __restrict__ d2max)
{
    const int tid  = threadIdx.x;
    const int lane = tid & 63;
    const int wave = tid >> 6;
    const int r0   = blockIdx.x * RPB;
    const float logb = params[1];

    _Float16* Eb = (_Float16*)outbuf;
    h8 E[RPB];

    #pragma unroll
    for (int r = 0; r < RPB; ++r)
        E[r] = __builtin_bit_cast(h8, *(const uint4*)(Eb + (size_t)(r0 + r) * 4096 + 8 * tid));

    if (FIRST) {
        const float invC10 = 10.0f * rsqrtf(__uint_as_float(*d2max));
        #pragma unroll
        for (int r = 0; r < RPB; ++r) {
            h8 e;
            #pragma unroll
            for (int c = 0; c < 8; ++c)
                e[c] = (_Float16)__expf(-(float)E[r][c] * invC10);
            E[r] = e;
            *(uint4*)(Eb + (size_t)(r0 + r) * 4096 + 8 * tid) = __builtin_bit_cast(uint4, e);
        }
    }

    float u8[8];
    if (FIRST) {
        #pragma unroll
        for (int c = 0; c < 8; ++c) u8[c] = 1.0f;
    } else {
        float4 sa = *(const float4*)(sigma + 8 * tid);
        float4 sb = *(const float4*)(sigma + 8 * tid + 4);
        u8[0] = (float)N_ROWS / sa.x; u8[1] = (float)N_ROWS / sa.y;
        u8[2] = (float)N_ROWS / sa.z; u8[3] = (float)N_ROWS / sa.w;
        u8[4] = (float)N_ROWS / sb.x; u8[5] = (float)N_ROWS / sb.y;
        u8[6] = (float)N_ROWS / sb.z; u8[7] = (float)N_ROWS / sb.w;
    }

    // pass A: row sums t_r
    float pr[RPB];
    #pragma unroll
    for (int r = 0; r < RPB; ++r) {
        float s = 0.0f;
        #pragma unroll
        for (int c = 0; c < 8; ++c) s += (float)E[r][c] * u8[c];
        pr[r] = s;
    }
    #pragma unroll
    for (int r = 0; r < RPB; ++r)
        #pragma unroll
        for (int off = 32; off > 0; off >>= 1)
            pr[r] += __shfl_xor(pr[r], off, 64);

    __shared__ float R[RPB][4];
    __shared__ float W[RPB];
    if (lane == 0)
        #pragma unroll
        for (int r = 0; r < RPB; ++r) R[r][wave] = pr[r];
    __syncthreads();
    if (tid < RPB) {
        float t = R[tid][0] + R[tid][1] + R[tid][2] + R[tid][3];
        float wr = __expf(-LAM * (logb + __logf(t)));
        W[tid] = wr;
        w[r0 + tid] = wr;
    }
    __syncthreads();

    // pass B: column partials sum_r E*w
    float p[8] = {0.f, 0.f, 0.f, 0.f, 0.f, 0.f, 0.f, 0.f};
    #pragma unroll
    for (int r = 0; r < RPB; ++r) {
        const float wr = W[r];
        #pragma unroll
        for (int c = 0; c < 8; ++c) p[c] += (float)E[r][c] * wr;
    }
    h8 ph;
    #pragma unroll
    for (int c = 0; c < 8; ++c) ph[c] = (_Float16)p[c];
    *(uint4*)(gpart + (size_t)blockIdx.x * M_COLS + 8 * tid) = __builtin_bit_cast(uint4, ph);
}

// sigma_j += partial column sums over a 64-row slab of gpart.
// grid = 64 blocks (8 col-groups x 8 row-groups) so 64 CUs work instead of 8;
// consumers compute u = N/sigma inline.
__global__ __launch_bounds__(256) void sk_gred(
    const _Float16* __restrict__ gpart, float* __restrict__ sigma)
{
    const int col = (blockIdx.x & 7) * 256 + threadIdx.x;
    const int b0  = (blockIdx.x >> 3) * (SKB / 8);
    float s = 0.0f;
    #pragma unroll 8
    for (int b = 0; b < SKB / 8; ++b)
        s += (float)gpart[(size_t)(b0 + b) * M_COLS + col];
    atomicAdd(&sigma[col], s);
}

// ---------------------------------------------------------------------------
// flow = E * w_r * u_j / (N*M)  (in-place: fp16 E rows -> fp32 flow rows)
// dist += sum cn * flow,  cn = -0.1*ln(E);  u_j = N / sigma_j (3rd iteration)
// All E rows loaded to registers, ONE barrier, then stores.
// ---------------------------------------------------------------------------
__global__ __launch_bounds__(256) void flow_dist(
    float* __restrict__ outbuf, const float* __restrict__ w,
    const float* __restrict__ sigma, float* __restrict__ dist)
{
    const int tid = threadIdx.x;
    const int r0  = blockIdx.x * RPB;
    const float invNM = 1.0f / ((float)N_ROWS * (float)M_COLS);
    _Float16* Eb = (_Float16*)outbuf;

    h8 E[RPB];
    #pragma unroll
    for (int r = 0; r < RPB; ++r)
        E[r] = __builtin_bit_cast(h8, *(const uint4*)(Eb + (size_t)(r0 + r) * 4096 + 8 * tid));

    __shared__ float W[RPB];
    if (tid < RPB) W[tid] = w[r0 + tid];

    float4 sA = *(const float4*)(sigma + 8 * tid);
    float4 sB = *(const float4*)(sigma + 8 * tid + 4);
    float u8[8];
    u8[0] = (float)N_ROWS / sA.x; u8[1] = (float)N_ROWS / sA.y;
    u8[2] = (float)N_ROWS / sA.z; u8[3] = (float)N_ROWS / sA.w;
    u8[4] = (float)N_ROWS / sB.x; u8[5] = (float)N_ROWS / sB.y;
    u8[6] = (float)N_ROWS / sB.z; u8[7] = (float)N_ROWS / sB.w;

    __syncthreads();   // drains all E loads + publishes W before any store

    float local = 0.0f;
    #pragma unroll
    for (int r = 0; r < RPB; ++r) {
        const float wr = W[r];
        float fl[8];
        #pragma unroll
        for (int c = 0; c < 8; ++c) {
            float e = (float)E[r][c];
            float o = e * wr * u8[c] * invNM;
            fl[c] = o;
            float cn = -0.1f * __logf(fmaxf(e, 1e-7f));
            local += cn * o;
        }
        float4 o0 = {fl[0], fl[1], fl[2], fl[3]};
        float4 o1 = {fl[4], fl[5], fl[6], fl[7]};
        float* frow = outbuf + (size_t)(r0 + r) * M_COLS + 8 * tid;
        *(float4*)frow = o0;
        *(float4*)(frow + 4) = o1;
    }

    __shared__ float red[256];
    red[tid] = local;
    __syncthreads();
    for (int s = 128; s > 0; s >>= 1) {
        if (tid < s) red[tid] += red[tid + s];
        __syncthreads();
    }
    if (tid == 0) atomicAdd(dist, red[0]);
}

// ---------------------------------------------------------------------------
extern "C" void kernel_launch(void* const* d_in, const int* in_sizes, int n_in,
                              void* d_out, int out_size, void* d_ws, size_t ws_size,
                              hipStream_t stream)
{
    const float* x     = (const float*)d_in[0];
    const float* y     = (const float*)d_in[1];
    const int*   iters = (const int*)d_in[2];
    const int*   ipe   = (const int*)d_in[3];
    float* out = (float*)d_out;
    float* ws  = (float*)d_ws;

    // ws layout (floats): ~4.2 MB total
    float*        params = ws;                       // [0]=rho [1]=logb
    unsigned int* d2max  = (unsigned int*)(ws + 8);
    float* w     = ws + 16;                          // 8192
    float* sigma = w + N_ROWS;                       // 3 * 2048
    float* mx = sigma + 3 * M_COLS;                  // 8192
    float* sx = mx + N_ROWS;                         // 8192
    float* x2 = sx + N_ROWS;                         // 8192
    float* my = x2 + N_ROWS;                         // 2048
    float* sy = my + M_COLS;                         // 2048
    float* y2 = sy + M_COLS;                         // 2048
    _Float16* gpart = (_Float16*)(y2 + M_COLS);      // 512*2048 fp16 = 2 MB

    float* sigma0 = sigma;
    float* sigma1 = sigma + M_COLS;
    float* sigma2 = sigma + 2 * M_COLS;

    float* dist = out + NM;

    k_init<<<8, 256, 0, stream>>>(iters, ipe, params, sigma, d2max, dist);
    rowstats_cvt<<<N_ROWS + M_COLS, 256, 0, stream>>>(
        x, y, (unsigned char*)out, mx, sx, x2, my, sy, y2);
    gemm_cost_mfma<<<dim3(M_COLS / 128, N_ROWS / 128), 256, 0, stream>>>(
        out, mx, sx, x2, my, sy, y2, d2max);

    sk_iter<true><<<SKB, 256, 0, stream>>>(out, nullptr, w, gpart, params, d2max);
    sk_gred<<<64, 256, 0, stream>>>(gpart, sigma0);
    sk_iter<false><<<SKB, 256, 0, stream>>>(out, sigma0, w, gpart, params, d2max);
    sk_gred<<<64, 256, 0, stream>>>(gpart, sigma1);
    sk_iter<false><<<SKB, 256, 0, stream>>>(out, sigma1, w, gpart, params, d2max);
    sk_gred<<<64, 256, 0, stream>>>(gpart, sigma2);

    flow_dist<<<SKB, 256, 0, stream>>>(out, w, sigma2, dist);
}